// Round 1
// 110.790 us; speedup vs baseline: 1.0318x; 1.0318x over previous
//
#include <hip/hip_runtime.h>
#include <hip/hip_bf16.h>
#include <math.h>

#define NQ 1024
#define BS 16
#define NC 256
#define NPRED (BS*NQ)   // 16384 pred boxes
#define MT 1024         // targets
#define MTPAD 1088      // +64 pad so prefetch of chunk c+1 never faults
#define GEPS 1e-6f

__device__ __forceinline__ float rcp_fast(float x) { return __builtin_amdgcn_rcpf(x); }
__device__ __forceinline__ float rfl(float x) {
    return __int_as_float(__builtin_amdgcn_readfirstlane(__float_as_int(x)));
}

// ---------------- Kernel 1: preprocess ----------------
// blocks [0, 4096): softmax row offset (4 rows/block, one wave per row)
//   rowoff[row] = rowmax + ln(sum exp(l - rowmax));  prob = exp(l - rowoff)
// blocks [4096, 4164): box extents
//   preds -> pext[n*8] = {mn0,mn1,mn2,mx0,mx1,mx2,vol,pad}
//   tgts  -> SoA streams (coalesced consumption in cost kernel):
//     tA[m]={mn0,mn1,mn2,mx0}  tB[m]={mx1,mx2,vol,label_bits}
//     tC[m]={b0,b1,b2,b3}      tD[m]={b4,b5}
__global__ __launch_bounds__(256) void prep_kernel(
    const float* __restrict__ logits,     // [NPRED, NC]
    const float* __restrict__ pcorners,   // [NPRED, 8, 3]
    const float* __restrict__ tcorners,   // [MT, 8, 3]
    const int*   __restrict__ tlabels,    // [MT]
    const float* __restrict__ tboxes,     // [MT, 6]
    float*  __restrict__ rowoff,          // [NPRED]
    float*  __restrict__ pext,            // [NPRED, 8]
    float4* __restrict__ tA,
    float4* __restrict__ tB,
    float4* __restrict__ tC,
    float2* __restrict__ tD)
{
    int t = threadIdx.x;
    int blk = blockIdx.x;
    if (blk < NPRED/4) {
        int wave = t >> 6, lane = t & 63;
        int row = blk*4 + wave;
        const float4 v = *(const float4*)(logits + (size_t)row*NC + lane*4);
        float mx = fmaxf(fmaxf(v.x, v.y), fmaxf(v.z, v.w));
        #pragma unroll
        for (int s = 1; s < 64; s <<= 1) mx = fmaxf(mx, __shfl_xor(mx, s));
        float e = __expf(v.x - mx) + __expf(v.y - mx) + __expf(v.z - mx) + __expf(v.w - mx);
        #pragma unroll
        for (int s = 1; s < 64; s <<= 1) e += __shfl_xor(e, s);
        if (lane == 0) rowoff[row] = mx + __logf(e);
    } else {
        int b = (blk - NPRED/4)*256 + t;
        bool is_pred = (b < NPRED);
        if (b >= NPRED + MT) return;
        int idx = is_pred ? b : (b - NPRED);
        const float* src = is_pred ? pcorners : tcorners;
        float buf[24];
        const float4* s4 = (const float4*)(src + (size_t)idx*24);
        #pragma unroll
        for (int i = 0; i < 6; ++i) *(float4*)&buf[i*4] = s4[i];
        float mn0 = buf[0], mn1 = buf[1], mn2 = buf[2];
        float mx0 = mn0, mx1 = mn1, mx2 = mn2;
        #pragma unroll
        for (int c = 1; c < 8; ++c) {
            mn0 = fminf(mn0, buf[c*3+0]); mx0 = fmaxf(mx0, buf[c*3+0]);
            mn1 = fminf(mn1, buf[c*3+1]); mx1 = fmaxf(mx1, buf[c*3+1]);
            mn2 = fminf(mn2, buf[c*3+2]); mx2 = fmaxf(mx2, buf[c*3+2]);
        }
        float vol = (mx0-mn0)*(mx1-mn1)*(mx2-mn2);
        if (is_pred) {
            *(float4*)(pext + (size_t)idx*8)     = make_float4(mn0, mn1, mn2, mx0);
            *(float4*)(pext + (size_t)idx*8 + 4) = make_float4(mx1, mx2, vol, 0.0f);
        } else {
            float2 b0 = *(const float2*)(tboxes + (size_t)idx*6);
            float2 b1 = *(const float2*)(tboxes + (size_t)idx*6 + 2);
            float2 b2 = *(const float2*)(tboxes + (size_t)idx*6 + 4);
            float lbf = __int_as_float(tlabels[idx]);
            tA[idx] = make_float4(mn0, mn1, mn2, mx0);
            tB[idx] = make_float4(mx1, mx2, vol, lbf);
            tC[idx] = make_float4(b0.x, b0.y, b1.x, b1.y);
            tD[idx] = make_float2(b2.x, b2.y);
        }
    }
}

// ---------------- Kernel 2: pairwise cost ----------------
// block = 16 n-rows x 512 m-cols. grid 2048 = 8 blocks/CU x 4 waves = 32 waves/CU.
// nt = blk & 1023, mt = blk >> 10 so the two blocks sharing a logit tile map to
// the same XCD (blk and blk+1024: same %8).
// Wave w owns rows w*4..w*4+3 (pred data wave-uniform -> SGPRs via readfirstlane).
// Prob tile is wave-private (each wave fills+reads only its own 4 rows) -> no barrier.
// Target data: SoA float4/float2 streams, fully coalesced; register-prefetched
// one chunk ahead to hide L2 latency.
__global__ __launch_bounds__(256) void cost_kernel(
    const float*  __restrict__ logits,   // [NPRED, NC]
    const float*  __restrict__ pboxes,   // [NPRED, 6]
    const float*  __restrict__ rowoff,   // [NPRED]
    const float*  __restrict__ pext,     // [NPRED, 8]
    const float4* __restrict__ tA,
    const float4* __restrict__ tB,
    const float4* __restrict__ tC,
    const float2* __restrict__ tD,
    float* __restrict__ out)             // [NPRED, MT]
{
    __shared__ float sProb[16][NC];
    const int t = threadIdx.x;
    const int nt = blockIdx.x & 1023;
    const int mt = blockIdx.x >> 10;
    const int n_base = nt * 16;
    const int m_base = mt * 512;
    const int lane = t & 63;
    const int wave = t >> 6;

    // Wave-local prob fill: wave w fills rows w*4..w*4+3 with exp(l - rowoff).
    // float4 loads + ds_write_b128; no __syncthreads needed (wave-private rows).
    #pragma unroll
    for (int r = 0; r < 4; ++r) {
        const int row = n_base + wave*4 + r;
        const float off = rowoff[row];
        const float4 v = *(const float4*)(logits + (size_t)row*NC + lane*4);
        float4 p;
        p.x = __expf(v.x - off); p.y = __expf(v.y - off);
        p.z = __expf(v.z - off); p.w = __expf(v.w - off);
        *(float4*)&sProb[wave*4 + r][lane*4] = p;
    }

    // Pred data for this wave's 4 rows -> SGPRs (wave-uniform)
    float smn[4][3], smx[4][3], svol[4], spb[4][6];
    #pragma unroll
    for (int i = 0; i < 4; ++i) {
        const int n = n_base + wave*4 + i;
        float4 a  = *(const float4*)(pext + (size_t)n*8);
        float4 b  = *(const float4*)(pext + (size_t)n*8 + 4);
        float2 c0 = *(const float2*)(pboxes + (size_t)n*6);
        float2 c1 = *(const float2*)(pboxes + (size_t)n*6 + 2);
        float2 c2 = *(const float2*)(pboxes + (size_t)n*6 + 4);
        smn[i][0]=rfl(a.x);  smn[i][1]=rfl(a.y);  smn[i][2]=rfl(a.z);
        smx[i][0]=rfl(a.w);  smx[i][1]=rfl(b.x);  smx[i][2]=rfl(b.y);
        svol[i]=rfl(b.z);
        spb[i][0]=rfl(c0.x); spb[i][1]=rfl(c0.y); spb[i][2]=rfl(c1.x);
        spb[i][3]=rfl(c1.y); spb[i][4]=rfl(c2.x); spb[i][5]=rfl(c2.y);
    }

    // out address of (row0, m_base+lane)
    const size_t out_idx0 = (size_t)(n_base + wave*4) * MT + m_base + lane;

    // Prefetch chunk 0
    int mi = m_base + lane;
    float4 a  = tA[mi];
    float4 b  = tB[mi];
    float4 cb = tC[mi];
    float2 db = tD[mi];

    #pragma unroll 1
    for (int c = 0; c < 8; ++c) {
        // Prefetch chunk c+1 (c=7 reads pad region [1024,1088): never used)
        const int mn_ = mi + (c+1)*64;
        const float4 a2  = tA[mn_];
        const float4 b2  = tB[mn_];
        const float4 cb2 = tC[mn_];
        const float2 db2 = tD[mn_];

        const float tmn0=a.x, tmn1=a.y, tmn2=a.z, tmx0=a.w;
        const float tmx1=b.x, tmx2=b.y, vt=b.z;
        const int lb = __float_as_int(b.w);

        float prv[4];
        #pragma unroll
        for (int i = 0; i < 4; ++i) prv[i] = sProb[wave*4+i][lb];

        #pragma unroll
        for (int i = 0; i < 4; ++i) {
            float dx = fminf(smx[i][0],tmx0) - fmaxf(smn[i][0],tmn0); dx = fmaxf(dx,0.f);
            float dy = fminf(smx[i][1],tmx1) - fmaxf(smn[i][1],tmn1); dy = fmaxf(dy,0.f);
            float dz = fminf(smx[i][2],tmx2) - fmaxf(smn[i][2],tmn2); dz = fmaxf(dz,0.f);
            float inter = dx*dy*dz;
            float uni   = svol[i] + vt - inter;
            float ex = fmaxf(smx[i][0],tmx0) - fminf(smn[i][0],tmn0);
            float ey = fmaxf(smx[i][1],tmx1) - fminf(smn[i][1],tmn1);
            float ez = fmaxf(smx[i][2],tmx2) - fminf(smn[i][2],tmn2);
            float enc = ex*ey*ez;
            float iou  = inter * rcp_fast(uni + GEPS);
            float giou = iou - (enc - uni) * rcp_fast(enc + GEPS);
            float l1 = fabsf(spb[i][0]-cb.x) + fabsf(spb[i][1]-cb.y) + fabsf(spb[i][2]-cb.z)
                     + fabsf(spb[i][3]-cb.w) + fabsf(spb[i][4]-db.x) + fabsf(spb[i][5]-db.y);
            __builtin_nontemporal_store(l1 - prv[i] - giou,
                                        out + out_idx0 + (size_t)i*MT + c*64);
        }
        a = a2; b = b2; cb = cb2; db = db2;
    }
}

extern "C" void kernel_launch(void* const* d_in, const int* in_sizes, int n_in,
                              void* d_out, int out_size, void* d_ws, size_t ws_size,
                              hipStream_t stream) {
    const float* logits   = (const float*)d_in[0];  // [16,1024,256]
    const float* pboxes   = (const float*)d_in[1];  // [16,1024,6]
    const float* pcorners = (const float*)d_in[2];  // [16,1024,8,3]
    const int*   tlabels  = (const int*)d_in[3];    // [1024]
    const float* tboxes   = (const float*)d_in[4];  // [1024,6]
    const float* tcorners = (const float*)d_in[5];  // [1024,8,3]
    float* out = (float*)d_out;

    float* ws = (float*)d_ws;
    float*  rowoff = ws;                               // 16384 floats
    float*  pext   = ws + 16384;                       // 131072 floats
    float4* tA = (float4*)(ws + 16384 + 131072);               // 1088 float4 = 4352 f
    float4* tB = (float4*)(ws + 16384 + 131072 + 4352);        // 4352 f
    float4* tC = (float4*)(ws + 16384 + 131072 + 8704);        // 4352 f
    float2* tD = (float2*)(ws + 16384 + 131072 + 13056);       // 2176 f
    // total ws use: 162,688 floats = 650,752 bytes (< 655,360 previously used)

    int prep_blocks = NPRED/4 + (NPRED + MT + 255)/256;   // 4096 + 68
    prep_kernel<<<prep_blocks, 256, 0, stream>>>(logits, pcorners, tcorners,
                                                 tlabels, tboxes, rowoff, pext,
                                                 tA, tB, tC, tD);
    cost_kernel<<<2048, 256, 0, stream>>>(logits, pboxes, rowoff, pext,
                                          tA, tB, tC, tD, out);
}